// Round 2
// baseline (175.761 us; speedup 1.0000x reference)
//
#include <hip/hip_runtime.h>
#include <math.h>

#define N 4096
#define D 512
#define NUM_STEPS 151
#define HALF_BINS 75
#define INV_STEP 75.0f
#define NUM_CLASSES 751
#define P_TOTAL 8386560.0f   // N*(N-1)/2, exact in fp32 (< 2^24)

// ws layout (float indices into d_ws)
#define WS_SUM_ALL 0
#define WS_POS_CNT 1          // int (total pos pairs, written by sort block in K1)
#define WS_SUM_POS 2
#define WS_S_POS   3
#define WS_DONE2   4          // int: done-counter for K2 (pospairs) last-block epilogue
#define WS_DONE3   5          // int: done-counter for K3 (gram) last-block epilogue
#define WS_G_OFF   8          // 151 floats
#define WS_LIST_OFF 1024
#define MAXP (1 << 18)        // 262144-entry pos-sim list (expect ~11K)
#define WS_FEAT_OFF (WS_LIST_OFF + MAXP)          // 4096x512 fp32 normalized feats
#define WS_FEATB_OFF (WS_FEAT_OFF + N * D)        // 4096x512 bf16 normalized feats (N*D/2 floats)
#define WS_IDX_OFF  (WS_FEATB_OFF + N * D / 2)    // N ints: row indices grouped by class
#define WS_OFFS_OFF (WS_IDX_OFF + N)              // NUM_CLASSES+1 ints: class row offsets
#define WS_POFF_OFF (WS_OFFS_OFF + NUM_CLASSES + 1) // NUM_CLASSES+1 ints: class pair offsets

#define POS_BLOCKS 128        // K2 grid: fewer blocks -> fewer release fences / done atomics

typedef __bf16 bf16x8 __attribute__((ext_vector_type(8)));
typedef float floatx4 __attribute__((ext_vector_type(4)));

// ---------------- K1: row L2-normalize (blocks 0..N-1) + class counting-sort
// ---------------- (block N), which also zeroes the accumulator header.
__global__ __launch_bounds__(256) void k_norm_sort(const float* __restrict__ feat,
                                                   const int* __restrict__ cls,
                                                   float* __restrict__ nf,
                                                   __bf16* __restrict__ nfb,
                                                   int* __restrict__ rowIdx,
                                                   int* __restrict__ offs,
                                                   int* __restrict__ pairOffs,
                                                   float* __restrict__ wsf,
                                                   int* __restrict__ wsi) {
    int t = threadIdx.x;
    if (blockIdx.x < N) {
        // ---- normalize one row ----
        int row = blockIdx.x;
        const float* fr = feat + (size_t)row * D;
        float a = fr[t];
        float b = fr[t + 256];
        float ss = a * a + b * b;
        for (int o = 32; o > 0; o >>= 1) ss += __shfl_down(ss, o, 64);
        __shared__ float wsum[4];
        int lane = t & 63, wid = t >> 6;
        if (lane == 0) wsum[wid] = ss;
        __syncthreads();
        float tot = wsum[0] + wsum[1] + wsum[2] + wsum[3];
        float inv = 1.0f / sqrtf(tot);
        float na = a * inv, nb = b * inv;
        nf[(size_t)row * D + t] = na;
        nf[(size_t)row * D + t + 256] = nb;
        nfb[(size_t)row * D + t] = (__bf16)na;
        nfb[(size_t)row * D + t + 256] = (__bf16)nb;
        return;
    }

    // ---- sort block: counting sort + prefix sums (rows AND pair slots) ----
    if (t == 0) {
        wsf[WS_SUM_ALL] = 0.f;
        wsf[WS_SUM_POS] = 0.f;
        wsi[WS_DONE2] = 0;
        wsi[WS_DONE3] = 0;
    }
    __shared__ int hcnt[NUM_CLASSES];
    __shared__ int hoff[NUM_CLASSES];
    __shared__ int poff[NUM_CLASSES];
    __shared__ int wsumR[4], wsumP[4];
    for (int c = t; c < NUM_CLASSES; c += 256) hcnt[c] = 0;
    __syncthreads();
    for (int n = t; n < N; n += 256) atomicAdd(&hcnt[cls[n]], 1);
    __syncthreads();

    // per-thread local sums over its 3 classes
    int c0 = t * 3;
    int cntPreR[3], cntPreP[3];
    int myR = 0, myP = 0;
    #pragma unroll
    for (int k = 0; k < 3; ++k) {
        int c = c0 + k;
        int cnt = (c < NUM_CLASSES) ? hcnt[c] : 0;
        cntPreR[k] = myR; cntPreP[k] = myP;       // exclusive-within-thread
        myR += cnt;
        myP += cnt * (cnt - 1) / 2;
    }
    // wave-level inclusive scan (64 lanes)
    int lane = t & 63, wv = t >> 6;
    int incR = myR, incP = myP;
    for (int o = 1; o < 64; o <<= 1) {
        int rr = __shfl_up(incR, o, 64);
        int pp = __shfl_up(incP, o, 64);
        if (lane >= o) { incR += rr; incP += pp; }
    }
    if (lane == 63) { wsumR[wv] = incR; wsumP[wv] = incP; }
    __syncthreads();
    int baseR = 0, baseP = 0;
    for (int w = 0; w < wv; ++w) { baseR += wsumR[w]; baseP += wsumP[w]; }
    int exR = baseR + incR - myR;                 // exclusive prefix for thread
    int exP = baseP + incP - myP;
    #pragma unroll
    for (int k = 0; k < 3; ++k) {
        int c = c0 + k;
        if (c < NUM_CLASSES) { hoff[c] = exR + cntPreR[k]; poff[c] = exP + cntPreP[k]; }
    }
    __syncthreads();

    // scatter rows grouped by class (LDS cursor atomics only)
    for (int c = t; c < NUM_CLASSES; c += 256) hcnt[c] = hoff[c];
    __syncthreads();
    for (int n = t; n < N; n += 256) {
        int p = atomicAdd(&hcnt[cls[n]], 1);
        rowIdx[p] = n;
    }
    for (int c = t; c < NUM_CLASSES; c += 256) { offs[c] = hoff[c]; pairOffs[c] = poff[c]; }
    if (t == 0) {
        int totR = wsumR[0] + wsumR[1] + wsumR[2] + wsumR[3];
        int totP = wsumP[0] + wsumP[1] + wsumP[2] + wsumP[3];
        offs[NUM_CLASSES] = totR;
        pairOffs[NUM_CLASSES] = totP;
        wsi[WS_POS_CNT] = totP;
    }
}

// ---------------- K2: within-class pair sims (deterministic slots, no atomics)
// ---------------- + last-done block builds hist_pos -> cdf -> G, sum_pos g.
// 128 blocks, class-strided: ~6 classes (~90 pairs) per block. Few release
// fences / done atomics; enough pair-iterations per wave to hide latency.
__global__ __launch_bounds__(256) void k_pos_cdf(const float* __restrict__ nf,
                                                 const int* __restrict__ rowIdx,
                                                 const int* __restrict__ offs,
                                                 const int* __restrict__ pairOffs,
                                                 float* __restrict__ posS,
                                                 float* __restrict__ G,
                                                 float* __restrict__ wsf,
                                                 int* __restrict__ wsi) {
    int t = threadIdx.x;
    int lane = t & 63;
    int wave = t >> 6;

    for (int c = blockIdx.x; c < NUM_CLASSES; c += POS_BLOCKS) {
        int o0 = offs[c], o1 = offs[c + 1];
        int nc = o1 - o0;
        if (nc < 2) continue;
        int nPairs = nc * (nc - 1) / 2;
        int pBase = pairOffs[c];
        for (int p = wave; p < nPairs; p += 4) {
            // decode pair p -> (a, b), a < b
            int a = 0, rem = p;
            while (rem >= nc - 1 - a) { rem -= nc - 1 - a; ++a; }
            int b = a + 1 + rem;
            int ri = rowIdx[o0 + a], rj = rowIdx[o0 + b];
            const float4* x4 = (const float4*)(nf + (size_t)ri * D);
            const float4* y4 = (const float4*)(nf + (size_t)rj * D);
            float4 xa = x4[lane * 2], xb = x4[lane * 2 + 1];
            float4 ya = y4[lane * 2], yb = y4[lane * 2 + 1];
            float s = xa.x * ya.x + xa.y * ya.y + xa.z * ya.z + xa.w * ya.w
                    + xb.x * yb.x + xb.y * yb.y + xb.z * yb.z + xb.w * yb.w;
            for (int o = 32; o > 0; o >>= 1) s += __shfl_down(s, o, 64);
            if (lane == 0) posS[pBase + p] = s;   // deterministic slot
        }
    }

    // ---- last-done block: build cdf ----
    __shared__ bool sdone;
    __syncthreads();
    if (t == 0) {
        __threadfence();                          // release posS writes
        int v = atomicAdd(&wsi[WS_DONE2], 1);
        sdone = (v == POS_BLOCKS - 1);
    }
    __syncthreads();
    if (!sdone) return;
    __threadfence();                              // acquire other blocks' posS

    __shared__ float sc[2][NUM_STEPS];
    __shared__ float Gs[NUM_STEPS];
    int C = wsi[WS_POS_CNT];
    if (C > MAXP) C = MAXP;
    for (int b = t; b < NUM_STEPS; b += 256) sc[0][b] = 0.f;
    __syncthreads();
    for (int p = t; p < C; p += 256) {
        float s = posS[p];
        float x = s * INV_STEP;
        float kf = floorf(x);
        float frac = x - kf;
        int kI = (int)kf;
        int lo = min(max(kI + HALF_BINS, 0), NUM_STEPS - 1);
        int hi = min(max(kI + HALF_BINS + 1, 0), NUM_STEPS - 1);
        atomicAdd(&sc[0][lo], 1.0f - frac);
        atomicAdd(&sc[0][hi], frac);
    }
    __syncthreads();
    // parallel inclusive scan over 151 bins (Hillis-Steele, double buffer)
    int src = 0;
    for (int o = 1; o < NUM_STEPS; o <<= 1) {
        if (t < NUM_STEPS) {
            float v = sc[src][t];
            if (t >= o) v += sc[src][t - o];
            sc[1 - src][t] = v;
        }
        __syncthreads();
        src ^= 1;
    }
    float invC = (C > 0) ? (1.0f / (float)C) : 0.f;
    if (t < NUM_STEPS) {
        float g = sc[src][t] * invC;
        Gs[t] = g;
        G[t] = g;
    }
    __syncthreads();

    float ps = 0.f;
    for (int p = t; p < C; p += 256) {
        float s = posS[p];
        float x = s * INV_STEP;
        float kf = floorf(x);
        float frac = x - kf;
        int kI = (int)kf;
        int lo = min(max(kI + HALF_BINS, 0), NUM_STEPS - 1);
        int hi = min(max(kI + HALF_BINS + 1, 0), NUM_STEPS - 1);
        ps += (1.f - frac) * Gs[lo] + frac * Gs[hi];
    }
    for (int o = 32; o > 0; o >>= 1) ps += __shfl_down(ps, o, 64);
    __shared__ float wsum[4];
    int wid = t >> 6;
    if ((t & 63) == 0) wsum[wid] = ps;
    __syncthreads();
    if (t == 0) {
        wsf[WS_SUM_POS] = wsum[0] + wsum[1] + wsum[2] + wsum[3];
        wsf[WS_S_POS] = (float)C;
    }
}

// ---------------- K3: upper-tri 128x128 MFMA Gram + g-lookup accumulate
// ---------------- + last-done block writes the final scalar.
#define TILES_1D 32            // 4096 / 128
#define LDSS 40                // LDS row stride in bf16 (32 + 8 pad; 2-way bank alias = free)

__global__ __launch_bounds__(256) void k_gram_final(const __bf16* __restrict__ nfb,
                                                    const float* __restrict__ G,
                                                    float* __restrict__ wsf,
                                                    int* __restrict__ wsi,
                                                    float* __restrict__ out) {
    // map linear block id -> upper-tri tile (ti, tj), tj >= ti
    int bid = blockIdx.x;
    int ti = 0, rem = bid;
    while (rem >= TILES_1D - ti) { rem -= TILES_1D - ti; ++ti; }
    int tj = ti + rem;

    __shared__ __align__(16) __bf16 As[128 * LDSS];
    __shared__ __align__(16) __bf16 Bs[128 * LDSS];
    __shared__ float Gs[NUM_STEPS];

    int tid = threadIdx.x;
    for (int b = tid; b < NUM_STEPS; b += 256) Gs[b] = G[b];

    int lane = tid & 63;
    int wave = tid >> 6;
    int wm = (wave >> 1) * 64;   // wave's 64-row region in A
    int wn = (wave & 1) * 64;    // wave's 64-row region in B
    int fr = lane & 15;          // row within 16 (A-row / B-row)
    int fk = (lane >> 4) * 8;    // k offset within BK

    int rowA0 = ti * 128, rowB0 = tj * 128;

    floatx4 acc[4][4] = {};

    // staging decomposition: 2 chunks of 8 bf16 per thread per matrix
    int e0 = tid * 8;            // chunk 0 element index (of 4096)
    int e1 = e0 + 2048;          // chunk 1
    int r0 = e0 >> 5, c0 = e0 & 31;
    int r1 = e1 >> 5, c1 = e1 & 31;

    for (int kb = 0; kb < D / 32; ++kb) {
        int kbase = kb * 32;
        *(float4*)(&As[r0 * LDSS + c0]) = *(const float4*)(nfb + (size_t)(rowA0 + r0) * D + kbase + c0);
        *(float4*)(&As[r1 * LDSS + c1]) = *(const float4*)(nfb + (size_t)(rowA0 + r1) * D + kbase + c1);
        *(float4*)(&Bs[r0 * LDSS + c0]) = *(const float4*)(nfb + (size_t)(rowB0 + r0) * D + kbase + c0);
        *(float4*)(&Bs[r1 * LDSS + c1]) = *(const float4*)(nfb + (size_t)(rowB0 + r1) * D + kbase + c1);
        __syncthreads();

        bf16x8 a[4], b[4];
        #pragma unroll
        for (int r = 0; r < 4; ++r)
            a[r] = *(const bf16x8*)(&As[(wm + r * 16 + fr) * LDSS + fk]);
        #pragma unroll
        for (int c = 0; c < 4; ++c)
            b[c] = *(const bf16x8*)(&Bs[(wn + c * 16 + fr) * LDSS + fk]);

        #pragma unroll
        for (int r = 0; r < 4; ++r)
            #pragma unroll
            for (int c = 0; c < 4; ++c)
                acc[r][c] = __builtin_amdgcn_mfma_f32_16x16x32_bf16(a[r], b[c], acc[r][c], 0, 0, 0);
        __syncthreads();
    }

    // epilogue: g(s) lookup with upper-triangle mask
    // C/D layout (16x16x32): col = lane&15 (B index), row = (lane>>4)*4 + reg (A index)
    int crow = (lane >> 4) * 4;
    int ccol = lane & 15;
    float gsum = 0.f;
    #pragma unroll
    for (int r = 0; r < 4; ++r) {
        #pragma unroll
        for (int c = 0; c < 4; ++c) {
            #pragma unroll
            for (int reg = 0; reg < 4; ++reg) {
                int gi = rowA0 + wm + r * 16 + crow + reg;
                int gj = rowB0 + wn + c * 16 + ccol;
                if (gi < gj) {
                    float s = acc[r][c][reg];
                    float x = s * INV_STEP;
                    float kf = floorf(x);
                    float frac = x - kf;
                    int kI = (int)kf;
                    int lo = min(max(kI + HALF_BINS, 0), NUM_STEPS - 1);
                    int hi = min(max(kI + HALF_BINS + 1, 0), NUM_STEPS - 1);
                    gsum += (1.f - frac) * Gs[lo] + frac * Gs[hi];
                }
            }
        }
    }
    for (int o = 32; o > 0; o >>= 1) gsum += __shfl_down(gsum, o, 64);
    __shared__ float wsum[4];
    if ((tid & 63) == 0) wsum[tid >> 6] = gsum;
    __syncthreads();
    if (tid == 0) atomicAdd(&wsf[WS_SUM_ALL], wsum[0] + wsum[1] + wsum[2] + wsum[3]);

    // ---- last-done block: final combine ----
    __shared__ bool sdone;
    if (tid == 0) {
        __threadfence();                          // release the atomicAdd above
        int v = atomicAdd(&wsi[WS_DONE3], 1);
        sdone = (v == (int)gridDim.x - 1);
    }
    __syncthreads();
    if (sdone && tid == 0) {
        __threadfence();                          // acquire other blocks' adds
        float sAll = atomicAdd(&wsf[WS_SUM_ALL], 0.0f);   // coherent read
        float C = wsf[WS_S_POS];                  // written last kernel (boundary-safe)
        float sneg = P_TOTAL - C;
        out[0] = (sAll - wsf[WS_SUM_POS]) / sneg;
    }
}

extern "C" void kernel_launch(void* const* d_in, const int* in_sizes, int n_in,
                              void* d_out, int out_size, void* d_ws, size_t ws_size,
                              hipStream_t stream) {
    const float* feat = (const float*)d_in[0];
    const int* cls = (const int*)d_in[1];
    float* out = (float*)d_out;
    float* wsf = (float*)d_ws;
    int* wsi = (int*)d_ws;

    float* nf = wsf + WS_FEAT_OFF;
    __bf16* nfb = (__bf16*)(wsf + WS_FEATB_OFF);
    float* posS = wsf + WS_LIST_OFF;
    float* G = wsf + WS_G_OFF;
    int* rowIdx = wsi + WS_IDX_OFF;
    int* offs = wsi + WS_OFFS_OFF;
    int* pairOffs = wsi + WS_POFF_OFF;

    // K1: normalize rows (blocks 0..N-1) + counting sort / header zero (block N)
    k_norm_sort<<<N + 1, 256, 0, stream>>>(feat, cls, nf, nfb, rowIdx, offs, pairOffs, wsf, wsi);
    // K2: pos-pair sims + fused cdf build (last-done block)
    k_pos_cdf<<<POS_BLOCKS, 256, 0, stream>>>(nf, rowIdx, offs, pairOffs, posS, G, wsf, wsi);
    // K3: Gram tiles + fused final combine (last-done block)
    int nTiles = TILES_1D * (TILES_1D + 1) / 2;   // 528 upper-tri 128x128 tiles
    k_gram_final<<<nTiles, 256, 0, stream>>>(nfb, G, wsf, wsi, out);
}

// Round 3
// 139.991 us; speedup vs baseline: 1.2555x; 1.2555x over previous
//
#include <hip/hip_runtime.h>
#include <math.h>

#define N 4096
#define D 512
#define NUM_STEPS 151
#define HALF_BINS 75
#define INV_STEP 75.0f
#define NUM_CLASSES 751
#define P_TOTAL 8386560.0f   // N*(N-1)/2, exact in fp32 (< 2^24)

// ws layout (float indices into d_ws)
#define WS_SUM_ALL 0
#define WS_POS_CNT 1          // int (total pos pairs, written by sort block in K1)
#define WS_SUM_POS 2
#define WS_S_POS   3
#define WS_DONE2   4          // int: done-counter for K2 last-block epilogue
#define WS_DONE3   5          // int: done-counter for K3 last-block epilogue
#define WS_G_OFF   8          // 151 floats: G (cdf of pos hist)
#define WS_H_OFF   160        // 151 floats: global pos histogram (atomic)
#define WS_LIST_OFF 1024
#define MAXP (1 << 18)        // packed pair list capacity (expect ~11K pairs)
#define WS_FEAT_OFF (WS_LIST_OFF + MAXP)          // 4096x512 fp32 normalized feats
#define WS_FEATB_OFF (WS_FEAT_OFF + N * D)        // 4096x512 bf16 normalized feats
#define WS_IDX_OFF  (WS_FEATB_OFF + N * D / 2)    // (unused, kept for layout stability)
#define WS_OFFS_OFF (WS_IDX_OFF + N)
#define WS_POFF_OFF (WS_OFFS_OFF + NUM_CLASSES + 1)

#define POS_BLOCKS 512        // K2 grid: 2048 waves -> ~5 pairs/wave

typedef __bf16 bf16x8 __attribute__((ext_vector_type(8)));
typedef float floatx4 __attribute__((ext_vector_type(4)));

// ---------------- K1: block 0 = counting-sort + packed pair-list build (+ header zero);
// ---------------- blocks 1..N = row L2-normalize. Sort block launches FIRST so its
// ---------------- serial work hides under the 4096 normalize blocks.
__global__ __launch_bounds__(256) void k_norm_sort(const float* __restrict__ feat,
                                                   const int* __restrict__ cls,
                                                   float* __restrict__ nf,
                                                   __bf16* __restrict__ nfb,
                                                   int* __restrict__ pairList,
                                                   float* __restrict__ wsf,
                                                   int* __restrict__ wsi) {
    int t = threadIdx.x;
    if (blockIdx.x > 0) {
        // ---- normalize one row ----
        int row = blockIdx.x - 1;
        const float* fr = feat + (size_t)row * D;
        float a = fr[t];
        float b = fr[t + 256];
        float ss = a * a + b * b;
        for (int o = 32; o > 0; o >>= 1) ss += __shfl_down(ss, o, 64);
        __shared__ float wsum[4];
        int lane = t & 63, wid = t >> 6;
        if (lane == 0) wsum[wid] = ss;
        __syncthreads();
        float tot = wsum[0] + wsum[1] + wsum[2] + wsum[3];
        float inv = 1.0f / sqrtf(tot);
        float na = a * inv, nb = b * inv;
        nf[(size_t)row * D + t] = na;
        nf[(size_t)row * D + t + 256] = nb;
        nfb[(size_t)row * D + t] = (__bf16)na;
        nfb[(size_t)row * D + t + 256] = (__bf16)nb;
        return;
    }

    // ---- sort block: counting sort + prefix sums + packed pair list ----
    if (t == 0) {
        wsf[WS_SUM_ALL] = 0.f;
        wsf[WS_SUM_POS] = 0.f;
        wsi[WS_DONE2] = 0;
        wsi[WS_DONE3] = 0;
    }
    {   // zero the global pos histogram
        float* histG = wsf + WS_H_OFF;
        for (int b = t; b < NUM_STEPS; b += 256) histG[b] = 0.f;
    }
    __shared__ int hcnt[NUM_CLASSES];
    __shared__ int hoff[NUM_CLASSES];
    __shared__ int poff[NUM_CLASSES];
    __shared__ int ridx[N];               // rows grouped by class (LDS-resident)
    __shared__ int wsumR[4], wsumP[4];
    for (int c = t; c < NUM_CLASSES; c += 256) hcnt[c] = 0;
    __syncthreads();
    for (int n = t; n < N; n += 256) atomicAdd(&hcnt[cls[n]], 1);
    __syncthreads();

    // per-thread local sums over its 3 classes
    int c0 = t * 3;
    int cntPreR[3], cntPreP[3];
    int myR = 0, myP = 0;
    #pragma unroll
    for (int k = 0; k < 3; ++k) {
        int c = c0 + k;
        int cnt = (c < NUM_CLASSES) ? hcnt[c] : 0;
        cntPreR[k] = myR; cntPreP[k] = myP;       // exclusive-within-thread
        myR += cnt;
        myP += cnt * (cnt - 1) / 2;
    }
    // wave-level inclusive scan (64 lanes)
    int lane = t & 63, wv = t >> 6;
    int incR = myR, incP = myP;
    for (int o = 1; o < 64; o <<= 1) {
        int rr = __shfl_up(incR, o, 64);
        int pp = __shfl_up(incP, o, 64);
        if (lane >= o) { incR += rr; incP += pp; }
    }
    if (lane == 63) { wsumR[wv] = incR; wsumP[wv] = incP; }
    __syncthreads();
    int baseR = 0, baseP = 0;
    for (int w = 0; w < wv; ++w) { baseR += wsumR[w]; baseP += wsumP[w]; }
    int exR = baseR + incR - myR;                 // exclusive prefix for thread
    int exP = baseP + incP - myP;
    #pragma unroll
    for (int k = 0; k < 3; ++k) {
        int c = c0 + k;
        if (c < NUM_CLASSES) { hoff[c] = exR + cntPreR[k]; poff[c] = exP + cntPreP[k]; }
    }
    __syncthreads();

    // scatter rows grouped by class into LDS (cursor atomics in LDS)
    for (int c = t; c < NUM_CLASSES; c += 256) hcnt[c] = hoff[c];
    __syncthreads();
    for (int n = t; n < N; n += 256) {
        int p = atomicAdd(&hcnt[cls[n]], 1);
        ridx[p] = n;
    }
    __syncthreads();

    // emit packed pair list: each thread owns its 3 classes
    #pragma unroll
    for (int k = 0; k < 3; ++k) {
        int c = c0 + k;
        if (c >= NUM_CLASSES) continue;
        int o0 = hoff[c];
        int nc = hcnt[c] - o0;                    // cursor ended at hoff+nc
        int pB = poff[c];
        int q = 0;
        for (int a = 0; a < nc - 1; ++a) {
            int ri = ridx[o0 + a];
            for (int b = a + 1; b < nc; ++b) {
                int rj = ridx[o0 + b];
                if (pB + q < MAXP) pairList[pB + q] = (ri << 12) | rj;
                ++q;
            }
        }
    }
    if (t == 0) {
        int totP = wsumP[0] + wsumP[1] + wsumP[2] + wsumP[3];
        wsi[WS_POS_CNT] = totP;
    }
}

// ---------------- K2: flat pair-sim histogram (LDS hist -> global atomic merge)
// ---------------- + last-done block: scan -> G, sum_pos = dot(hist, G).
__global__ __launch_bounds__(256) void k_pos_cdf(const float* __restrict__ nf,
                                                 const int* __restrict__ pairList,
                                                 float* __restrict__ histG,
                                                 float* __restrict__ G,
                                                 float* __restrict__ wsf,
                                                 int* __restrict__ wsi) {
    __shared__ float hloc[NUM_STEPS];
    int t = threadIdx.x;
    int lane = t & 63;
    int wave = t >> 6;
    for (int b = t; b < NUM_STEPS; b += 256) hloc[b] = 0.f;
    __syncthreads();

    int totP = wsi[WS_POS_CNT];
    if (totP > MAXP) totP = MAXP;
    const int STRIDE = POS_BLOCKS * 4;
    int p = blockIdx.x * 4 + wave;
    int vNext = (p < totP) ? pairList[p] : 0;     // prefetch
    for (; p < totP; p += STRIDE) {
        int v = vNext;
        int pn = p + STRIDE;
        if (pn < totP) vNext = pairList[pn];
        int ri = v >> 12, rj = v & 4095;
        const float4* x4 = (const float4*)(nf + (size_t)ri * D);
        const float4* y4 = (const float4*)(nf + (size_t)rj * D);
        float4 xa = x4[lane * 2], xb = x4[lane * 2 + 1];
        float4 ya = y4[lane * 2], yb = y4[lane * 2 + 1];
        float s = xa.x * ya.x + xa.y * ya.y + xa.z * ya.z + xa.w * ya.w
                + xb.x * yb.x + xb.y * yb.y + xb.z * yb.z + xb.w * yb.w;
        for (int o = 32; o > 0; o >>= 1) s += __shfl_down(s, o, 64);
        if (lane == 0) {
            float x = s * INV_STEP;
            float kf = floorf(x);
            float frac = x - kf;
            int kI = (int)kf;
            int lo = min(max(kI + HALF_BINS, 0), NUM_STEPS - 1);
            int hi = min(max(kI + HALF_BINS + 1, 0), NUM_STEPS - 1);
            atomicAdd(&hloc[lo], 1.0f - frac);
            atomicAdd(&hloc[hi], frac);
        }
    }
    __syncthreads();
    // merge block-local hist into global (device-coherent atomics)
    for (int b = t; b < NUM_STEPS; b += 256) {
        float v = hloc[b];
        if (v != 0.f) atomicAdd(&histG[b], v);
    }

    // ---- last-done block: cdf + sum_pos ----
    __shared__ bool sdone;
    __syncthreads();
    if (t == 0) {
        __threadfence();                          // drain hist atomics before done-inc
        int v = atomicAdd(&wsi[WS_DONE2], 1);
        sdone = (v == (int)gridDim.x - 1);
    }
    __syncthreads();
    if (!sdone) return;

    __shared__ float sc[2][NUM_STEPS];
    float hv = 0.f;
    if (t < NUM_STEPS) {
        hv = atomicAdd(&histG[t], 0.0f);          // coherent read of global hist
        sc[0][t] = hv;
    }
    __syncthreads();
    // parallel inclusive scan over 151 bins (Hillis-Steele, double buffer)
    int src = 0;
    for (int o = 1; o < NUM_STEPS; o <<= 1) {
        if (t < NUM_STEPS) {
            float v = sc[src][t];
            if (t >= o) v += sc[src][t - o];
            sc[1 - src][t] = v;
        }
        __syncthreads();
        src ^= 1;
    }
    float invC = (totP > 0) ? (1.0f / (float)totP) : 0.f;
    float prod = 0.f;
    if (t < NUM_STEPS) {
        float g = sc[src][t] * invC;
        G[t] = g;
        prod = hv * g;                            // sum_pos = dot(hist, G)
    }
    for (int o = 32; o > 0; o >>= 1) prod += __shfl_down(prod, o, 64);
    __shared__ float wsum[4];
    if ((t & 63) == 0) wsum[t >> 6] = prod;
    __syncthreads();
    if (t == 0) {
        wsf[WS_SUM_POS] = wsum[0] + wsum[1] + wsum[2] + wsum[3];
        wsf[WS_S_POS] = (float)totP;
    }
}

// ---------------- K3: upper-tri 128x128 MFMA Gram + g-lookup accumulate
// ---------------- + last-done block writes the final scalar.
#define TILES_1D 32            // 4096 / 128
#define LDSS 40                // LDS row stride in bf16 (32 + 8 pad; 2-way bank alias = free)

__global__ __launch_bounds__(256) void k_gram_final(const __bf16* __restrict__ nfb,
                                                    const float* __restrict__ G,
                                                    float* __restrict__ wsf,
                                                    int* __restrict__ wsi,
                                                    float* __restrict__ out) {
    // map linear block id -> upper-tri tile (ti, tj), tj >= ti
    int bid = blockIdx.x;
    int ti = 0, rem = bid;
    while (rem >= TILES_1D - ti) { rem -= TILES_1D - ti; ++ti; }
    int tj = ti + rem;

    __shared__ __align__(16) __bf16 As[128 * LDSS];
    __shared__ __align__(16) __bf16 Bs[128 * LDSS];
    __shared__ float Gs[NUM_STEPS];

    int tid = threadIdx.x;
    for (int b = tid; b < NUM_STEPS; b += 256) Gs[b] = G[b];

    int lane = tid & 63;
    int wave = tid >> 6;
    int wm = (wave >> 1) * 64;   // wave's 64-row region in A
    int wn = (wave & 1) * 64;    // wave's 64-row region in B
    int fr = lane & 15;          // row within 16 (A-row / B-row)
    int fk = (lane >> 4) * 8;    // k offset within BK

    int rowA0 = ti * 128, rowB0 = tj * 128;

    floatx4 acc[4][4] = {};

    // staging decomposition: 2 chunks of 8 bf16 per thread per matrix
    int e0 = tid * 8;            // chunk 0 element index (of 4096)
    int e1 = e0 + 2048;          // chunk 1
    int r0 = e0 >> 5, c0 = e0 & 31;
    int r1 = e1 >> 5, c1 = e1 & 31;

    for (int kb = 0; kb < D / 32; ++kb) {
        int kbase = kb * 32;
        *(float4*)(&As[r0 * LDSS + c0]) = *(const float4*)(nfb + (size_t)(rowA0 + r0) * D + kbase + c0);
        *(float4*)(&As[r1 * LDSS + c1]) = *(const float4*)(nfb + (size_t)(rowA0 + r1) * D + kbase + c1);
        *(float4*)(&Bs[r0 * LDSS + c0]) = *(const float4*)(nfb + (size_t)(rowB0 + r0) * D + kbase + c0);
        *(float4*)(&Bs[r1 * LDSS + c1]) = *(const float4*)(nfb + (size_t)(rowB0 + r1) * D + kbase + c1);
        __syncthreads();

        bf16x8 a[4], b[4];
        #pragma unroll
        for (int r = 0; r < 4; ++r)
            a[r] = *(const bf16x8*)(&As[(wm + r * 16 + fr) * LDSS + fk]);
        #pragma unroll
        for (int c = 0; c < 4; ++c)
            b[c] = *(const bf16x8*)(&Bs[(wn + c * 16 + fr) * LDSS + fk]);

        #pragma unroll
        for (int r = 0; r < 4; ++r)
            #pragma unroll
            for (int c = 0; c < 4; ++c)
                acc[r][c] = __builtin_amdgcn_mfma_f32_16x16x32_bf16(a[r], b[c], acc[r][c], 0, 0, 0);
        __syncthreads();
    }

    // epilogue: g(s) lookup with upper-triangle mask
    // C/D layout (16x16x32): col = lane&15 (B index), row = (lane>>4)*4 + reg (A index)
    int crow = (lane >> 4) * 4;
    int ccol = lane & 15;
    float gsum = 0.f;
    #pragma unroll
    for (int r = 0; r < 4; ++r) {
        #pragma unroll
        for (int c = 0; c < 4; ++c) {
            #pragma unroll
            for (int reg = 0; reg < 4; ++reg) {
                int gi = rowA0 + wm + r * 16 + crow + reg;
                int gj = rowB0 + wn + c * 16 + ccol;
                if (gi < gj) {
                    float s = acc[r][c][reg];
                    float x = s * INV_STEP;
                    float kf = floorf(x);
                    float frac = x - kf;
                    int kI = (int)kf;
                    int lo = min(max(kI + HALF_BINS, 0), NUM_STEPS - 1);
                    int hi = min(max(kI + HALF_BINS + 1, 0), NUM_STEPS - 1);
                    gsum += (1.f - frac) * Gs[lo] + frac * Gs[hi];
                }
            }
        }
    }
    for (int o = 32; o > 0; o >>= 1) gsum += __shfl_down(gsum, o, 64);
    __shared__ float wsum[4];
    if ((tid & 63) == 0) wsum[tid >> 6] = gsum;
    __syncthreads();
    if (tid == 0) atomicAdd(&wsf[WS_SUM_ALL], wsum[0] + wsum[1] + wsum[2] + wsum[3]);

    // ---- last-done block: final combine ----
    __shared__ bool sdone;
    if (tid == 0) {
        __threadfence();                          // release the atomicAdd above
        int v = atomicAdd(&wsi[WS_DONE3], 1);
        sdone = (v == (int)gridDim.x - 1);
    }
    __syncthreads();
    if (sdone && tid == 0) {
        __threadfence();                          // acquire other blocks' adds
        float sAll = atomicAdd(&wsf[WS_SUM_ALL], 0.0f);   // coherent read
        float C = wsf[WS_S_POS];                  // written last kernel (boundary-safe)
        float sneg = P_TOTAL - C;
        out[0] = (sAll - wsf[WS_SUM_POS]) / sneg;
    }
}

extern "C" void kernel_launch(void* const* d_in, const int* in_sizes, int n_in,
                              void* d_out, int out_size, void* d_ws, size_t ws_size,
                              hipStream_t stream) {
    const float* feat = (const float*)d_in[0];
    const int* cls = (const int*)d_in[1];
    float* out = (float*)d_out;
    float* wsf = (float*)d_ws;
    int* wsi = (int*)d_ws;

    float* nf = wsf + WS_FEAT_OFF;
    __bf16* nfb = (__bf16*)(wsf + WS_FEATB_OFF);
    int* pairList = wsi + WS_LIST_OFF;
    float* G = wsf + WS_G_OFF;
    float* histG = wsf + WS_H_OFF;

    // K1: sort/pair-list (block 0, scheduled first) + normalize rows (blocks 1..N)
    k_norm_sort<<<N + 1, 256, 0, stream>>>(feat, cls, nf, nfb, pairList, wsf, wsi);
    // K2: flat pair histogram + fused cdf/sum_pos (last-done block)
    k_pos_cdf<<<POS_BLOCKS, 256, 0, stream>>>(nf, pairList, histG, G, wsf, wsi);
    // K3: Gram tiles + fused final combine (last-done block)
    int nTiles = TILES_1D * (TILES_1D + 1) / 2;   // 528 upper-tri 128x128 tiles
    k_gram_final<<<nTiles, 256, 0, stream>>>(nfb, G, wsf, wsi, out);
}